// Round 3
// baseline (341.126 us; speedup 1.0000x reference)
//
#include <hip/hip_runtime.h>
#include <hip/hip_bf16.h>
#include <math.h>

#define MDIM 512
#define VDIM 50000
#define LSEQ 4096
#define EPW  50001     // Eprev/Enext row width
#define QPAD 528       // bf16 row stride (16B-aligned rows)
#define ITERS 6        // 5 unnormalized warm steps + 1 measured step
#define NWG  256       // 256 WGs x 16 rows = 4096 chunks
#define XTSTRIDE 4108  // ExTT row stride (floats); [4] front guard + [4096 data] + [8] tail guard
#define XTGUARD 4

typedef short short8 __attribute__((ext_vector_type(8)));
typedef float f32x4  __attribute__((ext_vector_type(4)));

__device__ __forceinline__ unsigned short f2bf(float f) {
    unsigned int x = __float_as_uint(f);
    unsigned int r = (x + 0x7fffu + ((x >> 16) & 1u)) >> 16;   // RNE
    return (unsigned short)r;
}

// ================= K1: fused prep =================
// blocks 0..511   : ExTT[j][t] = E[j, x[t]]  (row gather; E is L3-resident)
// blocks 512..639 : TmS bf16 MFMA-B-fragment swizzle
// blocks 640..655 : path score -> atomicAdd(out, -sum)
// block  656      : beta0 + logz0 -> atomicAdd(out, logz0)
__global__ __launch_bounds__(256) void k_prep(
        const float* __restrict__ T, const float* __restrict__ E,
        const float* __restrict__ Eprev, const float* __restrict__ Enext,
        const float* __restrict__ Cap, const int* __restrict__ x,
        const int* __restrict__ y, const int* __restrict__ upper,
        unsigned short* __restrict__ TmS, float* __restrict__ beta0,
        float* __restrict__ ExTT, float* __restrict__ out) {
    __shared__ int xs[4096];               // ext role: x staged; beta0 role: reduction buf
    int b = blockIdx.x, tid = threadIdx.x;

    if (b < 512) {
        // ---- ext gather: one block per state j ----
        int j = b;
        for (int t = tid; t < LSEQ; t += 256) xs[t] = x[t];
        __syncthreads();
        const float* Ej = E + (size_t)j * VDIM;
        float* dst = ExTT + (size_t)j * XTSTRIDE + XTGUARD;
        for (int t = tid; t < LSEQ; t += 256) dst[t] = Ej[xs[t]];
    } else if (b < 640) {
        // ---- Tm swizzle: frag g = jt<<10 | k16<<6 | lane ----
        int g = (b - 512) * 256 + tid;     // 0..32767
        int jt = g >> 10, k16 = (g >> 6) & 15, lane = g & 63;
        int n  = jt * 16 + (lane & 15);
        int kb = k16 * 32 + (lane >> 4) * 8;
        unsigned short tmp[8];
#pragma unroll
        for (int jj = 0; jj < 8; ++jj) tmp[jj] = f2bf(T[(kb + jj) * MDIM + n]);
        uint4 v;
        v.x = tmp[0] | ((unsigned)tmp[1] << 16);
        v.y = tmp[2] | ((unsigned)tmp[3] << 16);
        v.z = tmp[4] | ((unsigned)tmp[5] << 16);
        v.w = tmp[6] | ((unsigned)tmp[7] << 16);
        *(uint4*)(TmS + (size_t)g * 8) = v;
    } else if (b < 656) {
        // ---- path score ----
        int t = (b - 640) * 256 + tid;     // 0..4095
        int yt = y[t];
        int yp = (t == 0) ? MDIM : y[t - 1];
        int xp = (t == 0) ? MDIM : x[t - 1];
        int xn = (t == LSEQ - 1) ? MDIM : x[t + 1];
        float v = T[yp * MDIM + yt] + Eprev[yt * EPW + xp] + Enext[yt * EPW + xn]
                + Cap[yt * 2 + upper[t]] + E[(size_t)yt * VDIM + x[t]];
#pragma unroll
        for (int m = 1; m < 64; m <<= 1) v += __shfl_xor(v, m);
        if ((tid & 63) == 0) atomicAdd(out, -v);
    } else {
        // ---- beta0 + logz0: thread handles states tid and tid+256 ----
        float* red = (float*)xs;
        int x0 = x[0], x1 = x[1], u0 = upper[0];
        float e0, e1;
#pragma unroll
        for (int h = 0; h < 2; ++h) {
            int i = tid + h * 256;
            float phi = T[MDIM * MDIM + i] + Eprev[i * EPW + MDIM] + Enext[i * EPW + x1]
                      + Cap[i * 2 + u0] + E[(size_t)i * VDIM + x0];
            float e = expf(phi);
            if (h == 0) e0 = e; else e1 = e;
        }
        red[tid] = e0 + e1;
        __syncthreads();
        for (int s = 128; s > 0; s >>= 1) {
            if (tid < s) red[tid] += red[tid + s];
            __syncthreads();
        }
        float s0 = red[0];
        beta0[tid] = e0 / s0;
        beta0[tid + 256] = e1 / s0;
        if (tid == 0) atomicAdd(out, logf(s0));
    }
}

// ================= K2: chunked forward scan =================
// Chunk c = wg*16 + r measures step t_real = c+1 at iter ITERS-1 (ratio trick).
// Iter i: step t = tw0 + r + i, tw0 = 16*wg - (ITERS-2). All steps unnormalized;
// S0 (i=ITERS-2) and S1 (i=ITERS-1) row sums -> contribution log(S1/S0).
// t==1 rows get exact beta0 injected (sum=1); S0==0 -> 1.
//
// 1024 threads = 16 waves, PURE STREAMING of Tm from L2 (TmS = 512KB, resident
// in each XCD's 4MB L2 since all 32 CUs re-read it every iter). NO register
// residence: with MFMA the compiler splits the 128-reg/wave cap (forced by the
// 1024-thr block) into 64 ArchVGPR + 64 AGPR, so any resident Tm slice spills
// (R1: 48MB, R2: 83MB scratch writes). Dual 4-deep rolling prefetch fits ~60
// ArchVGPRs -> zero spills; 4 waves/SIMD hide the L2 latency.
__global__ __launch_bounds__(1024, 4) void k_chunks(const unsigned short* __restrict__ TmS,
                                                    const float* __restrict__ beta0,
                                                    const float* __restrict__ ExTT,
                                                    float* __restrict__ out) {
    __shared__ __align__(16) unsigned short Q[16 * QPAD];
    __shared__ float S0[16], S1[16];
    int tid  = threadIdx.x;
    int wg   = blockIdx.x;
    int wave = tid >> 6;        // 0..15
    int lane = tid & 63;
    int quad = lane >> 4;
    int l16  = lane & 15;
    int tw0  = 16 * wg - (ITERS - 2);

    const unsigned short* tmb0 = TmS + (size_t)((wave * 16) * 64 + lane) * 8;
    const unsigned short* tmb1 = TmS + (size_t)(((wave + 16) * 16) * 64 + lane) * 8;

    unsigned short uinit = f2bf(1.0f / 512.0f);
    for (int idx = tid; idx < 16 * MDIM; idx += 1024) {
        int r = idx >> 9, j = idx & 511;
        Q[r * QPAD + j] = uinit;
    }
    if (tid < 16) { S0[tid] = 0.f; S1[tid] = 0.f; }
    __syncthreads();

    for (int i = 0; i < ITERS; ++i) {
        // ---- A: inject exact beta0 into the row whose step is t==1 this iter
        int rinj = 1 - tw0 - i;
        if (rinj >= 0 && rinj < 16 && tid < MDIM) Q[rinj * QPAD + tid] = f2bf(beta0[tid]);
        __syncthreads();   // orders injection + prev D-writes before B-reads

        // ---- ev prefetch: 4 scalar floats per p (t_base..t_base+3), guarded region
        int t_base = tw0 + quad * 4 + i;   // reg r -> t = t_base + r
        float ev[2][4];
#pragma unroll
        for (int p = 0; p < 2; ++p) {
            int col = (wave + p * 16) * 16 + l16;
            const float* src = ExTT + (size_t)col * XTSTRIDE + XTGUARD + t_base;
#pragma unroll
            for (int reg = 0; reg < 4; ++reg) ev[p][reg] = src[reg];
        }

        // ---- B: G(16x512) = Q @ Tm, both halves streamed with rolling prefetch
        short8 b0[4], b1[4];
#pragma unroll
        for (int k = 0; k < 4; ++k) {
            b0[k] = *(const short8*)(tmb0 + (size_t)k * 512);
            b1[k] = *(const short8*)(tmb1 + (size_t)k * 512);
        }
        f32x4 acc0 = (f32x4){0.f, 0.f, 0.f, 0.f};
        f32x4 acc1 = (f32x4){0.f, 0.f, 0.f, 0.f};
#pragma unroll
        for (int k16 = 0; k16 < 16; ++k16) {
            short8 a = *(const short8*)&Q[l16 * QPAD + k16 * 32 + quad * 8];
            acc0 = __builtin_amdgcn_mfma_f32_16x16x32_bf16(a, b0[k16 & 3], acc0, 0, 0, 0);
            acc1 = __builtin_amdgcn_mfma_f32_16x16x32_bf16(a, b1[k16 & 3], acc1, 0, 0, 0);
            if (k16 < 12) {
                b0[k16 & 3] = *(const short8*)(tmb0 + (size_t)(k16 + 4) * 512);
                b1[k16 & 3] = *(const short8*)(tmb1 + (size_t)(k16 + 4) * 512);
            }
        }
        __syncthreads();   // all Q reads done before rewrite

        // ---- C: alpha = G .* ext; reduce row sums on last two iters only
        bool red = (i >= ITERS - 2);
        float* Sx = (i == ITERS - 2) ? S0 : S1;
        float av0[4], av1[4];
        float srow[4];
#pragma unroll
        for (int reg = 0; reg < 4; ++reg) {
            int t = t_base + reg;
            bool ok = (t >= 1 && t < LSEQ);
            float v0 = ok ? acc0[reg] * ev[0][reg] : 0.f;
            float v1 = ok ? acc1[reg] * ev[1][reg] : 0.f;
            av0[reg] = v0;
            av1[reg] = v1;
            if (red) {
                float sv = v0 + v1;        // both p land in the same row quad*4+reg
                sv += __shfl_xor(sv, 1);
                sv += __shfl_xor(sv, 2);
                sv += __shfl_xor(sv, 4);
                sv += __shfl_xor(sv, 8);
                srow[reg] = sv;
            }
        }
        if (red && l16 == 0) {
#pragma unroll
            for (int reg = 0; reg < 4; ++reg)
                atomicAdd(&Sx[quad * 4 + reg], srow[reg]);
        }

        // ---- D: write back bf16 (skip after final step)
        if (i < ITERS - 1) {
#pragma unroll
            for (int p = 0; p < 2; ++p) {
                int col = (wave + p * 16) * 16 + l16;
#pragma unroll
                for (int reg = 0; reg < 4; ++reg) {
                    int row = quad * 4 + reg;
                    int t = t_base + reg;
                    if (t >= 1 && t < LSEQ)
                        Q[row * QPAD + col] = f2bf(p ? av1[reg] : av0[reg]);
                }
            }
        }
        // no trailing barrier: next iter's post-A barrier orders D before B-reads;
        // the next injection row had t==0 here -> its D write was guarded out.
    }
    __syncthreads();   // S0/S1 atomicAdds complete before read

    if (wave == 0) {
        float lv = 0.f;
        int tr = 16 * wg + lane + 1;
        if (lane < 16 && tr < LSEQ) {
            float s0 = S0[lane];
            if (s0 == 0.f) s0 = 1.f;   // t_real==1 row: injected beta0 has sum 1
            lv = logf(S1[lane] / s0);
        }
#pragma unroll
        for (int m = 1; m < 64; m <<= 1) lv += __shfl_xor(lv, m);
        if (lane == 0) atomicAdd(out, lv);
    }
}

extern "C" void kernel_launch(void* const* d_in, const int* in_sizes, int n_in,
                              void* d_out, int out_size, void* d_ws, size_t ws_size,
                              hipStream_t stream) {
    const float* T     = (const float*)d_in[0];
    const float* E     = (const float*)d_in[1];
    const float* Eprev = (const float*)d_in[2];
    const float* Enext = (const float*)d_in[3];
    const float* Cap   = (const float*)d_in[4];
    const int*   x     = (const int*)d_in[5];
    const int*   y     = (const int*)d_in[6];
    const int*   upper = (const int*)d_in[7];
    float* out = (float*)d_out;

    // ws: [0,512K) TmS | [512K,+2K) beta0 | ExTT 512*4108*4 B ~= 8.41 MB. Total ~8.94 MB.
    char* ws = (char*)d_ws;
    unsigned short* TmS = (unsigned short*)ws;
    float* beta0 = (float*)(ws + 524288);
    float* ExTT  = (float*)(ws + 524288 + 2048);

    hipMemsetAsync(out, 0, sizeof(float), stream);
    k_prep<<<657, 256, 0, stream>>>(T, E, Eprev, Enext, Cap, x, y, upper,
                                    TmS, beta0, ExTT, out);
    k_chunks<<<NWG, 1024, 0, stream>>>(TmS, beta0, ExTT, out);
}

// Round 4
// 297.341 us; speedup vs baseline: 1.1473x; 1.1473x over previous
//
#include <hip/hip_runtime.h>
#include <hip/hip_bf16.h>
#include <math.h>

#define MDIM 512
#define VDIM 50000
#define LSEQ 4096
#define EPW  50001     // Eprev/Enext row width
#define QPAD 528       // bf16 row stride (16B-aligned rows)
#define ITERS 6        // 5 unnormalized warm steps + 1 measured step
#define NWG  256       // 256 WGs x 16 rows = 4096 chunks
#define XTSTRIDE 4108  // ExTT row stride (floats); [4] front guard + [4096 data] + [8] tail guard
#define XTGUARD 4

typedef short short8 __attribute__((ext_vector_type(8)));
typedef float f32x4  __attribute__((ext_vector_type(4)));

__device__ __forceinline__ unsigned short f2bf(float f) {
    unsigned int x = __float_as_uint(f);
    unsigned int r = (x + 0x7fffu + ((x >> 16) & 1u)) >> 16;   // RNE
    return (unsigned short)r;
}

// async global(16B/lane) -> LDS(base + lane*16); lds base must be wave-uniform
#define GLOAD16(gsrc, ldst) \
    __builtin_amdgcn_global_load_lds((__attribute__((address_space(1))) void*)(gsrc), \
                                     (__attribute__((address_space(3))) void*)(ldst), 16, 0, 0)

// ================= K1: fused prep =================
// blocks 0..511   : ExTT[j][t] = E[j, x[t]]  (row gather; E is L3-resident)
// blocks 512..639 : TmS bf16 MFMA-B-fragment swizzle
// blocks 640..655 : path score -> atomicAdd(out, -sum)
// block  656      : beta0 + logz0 -> atomicAdd(out, logz0)
__global__ __launch_bounds__(256) void k_prep(
        const float* __restrict__ T, const float* __restrict__ E,
        const float* __restrict__ Eprev, const float* __restrict__ Enext,
        const float* __restrict__ Cap, const int* __restrict__ x,
        const int* __restrict__ y, const int* __restrict__ upper,
        unsigned short* __restrict__ TmS, float* __restrict__ beta0,
        float* __restrict__ ExTT, float* __restrict__ out) {
    __shared__ int xs[4096];               // ext role: x staged; beta0 role: reduction buf
    int b = blockIdx.x, tid = threadIdx.x;

    if (b < 512) {
        // ---- ext gather: one block per state j ----
        int j = b;
        for (int t = tid; t < LSEQ; t += 256) xs[t] = x[t];
        __syncthreads();
        const float* Ej = E + (size_t)j * VDIM;
        float* dst = ExTT + (size_t)j * XTSTRIDE + XTGUARD;
        for (int t = tid; t < LSEQ; t += 256) dst[t] = Ej[xs[t]];
    } else if (b < 640) {
        // ---- Tm swizzle: frag g = jt<<10 | k16<<6 | lane ----
        int g = (b - 512) * 256 + tid;     // 0..32767
        int jt = g >> 10, k16 = (g >> 6) & 15, lane = g & 63;
        int n  = jt * 16 + (lane & 15);
        int kb = k16 * 32 + (lane >> 4) * 8;
        unsigned short tmp[8];
#pragma unroll
        for (int jj = 0; jj < 8; ++jj) tmp[jj] = f2bf(T[(kb + jj) * MDIM + n]);
        uint4 v;
        v.x = tmp[0] | ((unsigned)tmp[1] << 16);
        v.y = tmp[2] | ((unsigned)tmp[3] << 16);
        v.z = tmp[4] | ((unsigned)tmp[5] << 16);
        v.w = tmp[6] | ((unsigned)tmp[7] << 16);
        *(uint4*)(TmS + (size_t)g * 8) = v;
    } else if (b < 656) {
        // ---- path score ----
        int t = (b - 640) * 256 + tid;     // 0..4095
        int yt = y[t];
        int yp = (t == 0) ? MDIM : y[t - 1];
        int xp = (t == 0) ? MDIM : x[t - 1];
        int xn = (t == LSEQ - 1) ? MDIM : x[t + 1];
        float v = T[yp * MDIM + yt] + Eprev[yt * EPW + xp] + Enext[yt * EPW + xn]
                + Cap[yt * 2 + upper[t]] + E[(size_t)yt * VDIM + x[t]];
#pragma unroll
        for (int m = 1; m < 64; m <<= 1) v += __shfl_xor(v, m);
        if ((tid & 63) == 0) atomicAdd(out, -v);
    } else {
        // ---- beta0 + logz0: thread handles states tid and tid+256 ----
        float* red = (float*)xs;
        int x0 = x[0], x1 = x[1], u0 = upper[0];
        float e0, e1;
#pragma unroll
        for (int h = 0; h < 2; ++h) {
            int i = tid + h * 256;
            float phi = T[MDIM * MDIM + i] + Eprev[i * EPW + MDIM] + Enext[i * EPW + x1]
                      + Cap[i * 2 + u0] + E[(size_t)i * VDIM + x0];
            float e = expf(phi);
            if (h == 0) e0 = e; else e1 = e;
        }
        red[tid] = e0 + e1;
        __syncthreads();
        for (int s = 128; s > 0; s >>= 1) {
            if (tid < s) red[tid] += red[tid + s];
            __syncthreads();
        }
        float s0 = red[0];
        beta0[tid] = e0 / s0;
        beta0[tid + 256] = e1 / s0;
        if (tid == 0) atomicAdd(out, logf(s0));
    }
}

// ================= K2: chunked forward scan =================
// Chunk c = wg*16 + r measures step t_real = c+1 at iter ITERS-1 (ratio trick).
// Iter i: step t = tw0 + r + i, tw0 = 16*wg - (ITERS-2). All steps unnormalized;
// S0 (i=ITERS-2) and S1 (i=ITERS-1) row sums -> contribution log(S1/S0).
// t==1 rows get exact beta0 injected (sum=1); S0==0 -> 1.
//
// 1024 threads = 16 waves. Tm is staged into LDS via global_load_lds, double-
// buffered per k16-phase. Wave w consumes ONLY fragments jt=w and w+16, and
// the DMA writes lds_base + lane*16 which exactly matches the fragment layout
// -> each wave stages its own 2 slots, no cross-wave sharing, no extra
// barriers; per-wave counted-vmcnt pipeline (never drained mid-loop).
// This removes ALL Tm register residence (R0-R3: 48-128 MB scratch spills,
// perfectly correlated with dur) -> ~40 arch VGPRs, zero spills.
__global__ __launch_bounds__(1024, 4) void k_chunks(const unsigned short* __restrict__ TmS,
                                                    const float* __restrict__ beta0,
                                                    const float* __restrict__ ExTT,
                                                    float* __restrict__ out) {
    __shared__ __align__(16) unsigned short Q[16 * QPAD];
    __shared__ __align__(16) unsigned short Bst[2][32][512];   // 64 KB: [buf][jt-slot][lane*8]
    __shared__ float S0[16], S1[16];
    int tid  = threadIdx.x;
    int wg   = blockIdx.x;
    int wave = tid >> 6;        // 0..15
    int lane = tid & 63;
    int quad = lane >> 4;
    int l16  = lane & 15;
    int tw0  = 16 * wg - (ITERS - 2);

    const unsigned short* tmb0 = TmS + (size_t)((wave * 16) * 64 + lane) * 8;         // jt = wave
    const unsigned short* tmb1 = TmS + (size_t)(((wave + 16) * 16) * 64 + lane) * 8;  // jt = wave+16

    unsigned short uinit = f2bf(1.0f / 512.0f);
    for (int idx = tid; idx < 16 * MDIM; idx += 1024) {
        int r = idx >> 9, j = idx & 511;
        Q[r * QPAD + j] = uinit;
    }
    if (tid < 16) { S0[tid] = 0.f; S1[tid] = 0.f; }
    __syncthreads();

    for (int i = 0; i < ITERS; ++i) {
        // ---- A: inject exact beta0 into the row whose step is t==1 this iter
        int rinj = 1 - tw0 - i;
        if (rinj >= 0 && rinj < 16 && tid < MDIM) Q[rinj * QPAD + tid] = f2bf(beta0[tid]);
        __syncthreads();   // orders injection + prev D-writes before B-reads (drains vmcnt too)

        // ---- stage k16=0 first (starts the L2 stream earliest)
        GLOAD16(tmb0, &Bst[0][wave][0]);
        GLOAD16(tmb1, &Bst[0][wave + 16][0]);

        // ---- ev prefetch: 4 scalar floats per p (t_base..t_base+3), guarded region
        int t_base = tw0 + quad * 4 + i;   // reg r -> t = t_base + r
        float ev[2][4];
#pragma unroll
        for (int p = 0; p < 2; ++p) {
            int col = (wave + p * 16) * 16 + l16;
            const float* src = ExTT + (size_t)col * XTSTRIDE + XTGUARD + t_base;
#pragma unroll
            for (int reg = 0; reg < 4; ++reg) ev[p][reg] = src[reg];
        }

        // ---- B: G(16x512) = Q @ Tm, Tm via LDS double-buffer, counted vmcnt
        f32x4 acc0 = (f32x4){0.f, 0.f, 0.f, 0.f};
        f32x4 acc1 = (f32x4){0.f, 0.f, 0.f, 0.f};
#pragma unroll
        for (int k16 = 0; k16 < 16; ++k16) {
            if (k16 < 15) {
                int nb = (k16 + 1) & 1;
                GLOAD16(tmb0 + (size_t)(k16 + 1) * 512, &Bst[nb][wave][0]);
                GLOAD16(tmb1 + (size_t)(k16 + 1) * 512, &Bst[nb][wave + 16][0]);
            }
            // in-flight order: [stage k16 (2)] [ev (8, k16==0 only)] [stage k16+1 (2)]
            // wait so that stage k16 is complete; keep the newest loads in flight.
            if (k16 == 0)       asm volatile("s_waitcnt vmcnt(10)" ::: "memory");
            else if (k16 < 15)  asm volatile("s_waitcnt vmcnt(2)"  ::: "memory");
            else                asm volatile("s_waitcnt vmcnt(0)"  ::: "memory");
            short8 a  = *(const short8*)&Q[l16 * QPAD + k16 * 32 + quad * 8];
            short8 b0 = *(const short8*)&Bst[k16 & 1][wave][lane * 8];
            short8 b1 = *(const short8*)&Bst[k16 & 1][wave + 16][lane * 8];
            acc0 = __builtin_amdgcn_mfma_f32_16x16x32_bf16(a, b0, acc0, 0, 0, 0);
            acc1 = __builtin_amdgcn_mfma_f32_16x16x32_bf16(a, b1, acc1, 0, 0, 0);
        }
        __syncthreads();   // all Q reads done before rewrite

        // ---- C: alpha = G .* ext; reduce row sums on last two iters only
        bool red = (i >= ITERS - 2);
        float* Sx = (i == ITERS - 2) ? S0 : S1;
        float av0[4], av1[4];
        float srow[4];
#pragma unroll
        for (int reg = 0; reg < 4; ++reg) {
            int t = t_base + reg;
            bool ok = (t >= 1 && t < LSEQ);
            float v0 = ok ? acc0[reg] * ev[0][reg] : 0.f;
            float v1 = ok ? acc1[reg] * ev[1][reg] : 0.f;
            av0[reg] = v0;
            av1[reg] = v1;
            if (red) {
                float sv = v0 + v1;        // both p land in the same row quad*4+reg
                sv += __shfl_xor(sv, 1);
                sv += __shfl_xor(sv, 2);
                sv += __shfl_xor(sv, 4);
                sv += __shfl_xor(sv, 8);
                srow[reg] = sv;
            }
        }
        if (red && l16 == 0) {
#pragma unroll
            for (int reg = 0; reg < 4; ++reg)
                atomicAdd(&Sx[quad * 4 + reg], srow[reg]);
        }

        // ---- D: write back bf16 (skip after final step)
        if (i < ITERS - 1) {
#pragma unroll
            for (int p = 0; p < 2; ++p) {
                int col = (wave + p * 16) * 16 + l16;
#pragma unroll
                for (int reg = 0; reg < 4; ++reg) {
                    int row = quad * 4 + reg;
                    int t = t_base + reg;
                    if (t >= 1 && t < LSEQ)
                        Q[row * QPAD + col] = f2bf(p ? av1[reg] : av0[reg]);
                }
            }
        }
        // no trailing barrier: next iter's post-A barrier orders D before B-reads;
        // the next injection row had t==0 here -> its D write was guarded out.
    }
    __syncthreads();   // S0/S1 atomicAdds complete before read

    if (wave == 0) {
        float lv = 0.f;
        int tr = 16 * wg + lane + 1;
        if (lane < 16 && tr < LSEQ) {
            float s0 = S0[lane];
            if (s0 == 0.f) s0 = 1.f;   // t_real==1 row: injected beta0 has sum 1
            lv = logf(S1[lane] / s0);
        }
#pragma unroll
        for (int m = 1; m < 64; m <<= 1) lv += __shfl_xor(lv, m);
        if (lane == 0) atomicAdd(out, lv);
    }
}

extern "C" void kernel_launch(void* const* d_in, const int* in_sizes, int n_in,
                              void* d_out, int out_size, void* d_ws, size_t ws_size,
                              hipStream_t stream) {
    const float* T     = (const float*)d_in[0];
    const float* E     = (const float*)d_in[1];
    const float* Eprev = (const float*)d_in[2];
    const float* Enext = (const float*)d_in[3];
    const float* Cap   = (const float*)d_in[4];
    const int*   x     = (const int*)d_in[5];
    const int*   y     = (const int*)d_in[6];
    const int*   upper = (const int*)d_in[7];
    float* out = (float*)d_out;

    // ws: [0,512K) TmS | [512K,+2K) beta0 | ExTT 512*4108*4 B ~= 8.41 MB. Total ~8.94 MB.
    char* ws = (char*)d_ws;
    unsigned short* TmS = (unsigned short*)ws;
    float* beta0 = (float*)(ws + 524288);
    float* ExTT  = (float*)(ws + 524288 + 2048);

    hipMemsetAsync(out, 0, sizeof(float), stream);
    k_prep<<<657, 256, 0, stream>>>(T, E, Eprev, Enext, Cap, x, y, upper,
                                    TmS, beta0, ExTT, out);
    k_chunks<<<NWG, 1024, 0, stream>>>(TmS, beta0, ExTT, out);
}

// Round 5
// 294.528 us; speedup vs baseline: 1.1582x; 1.0096x over previous
//
#include <hip/hip_runtime.h>
#include <hip/hip_bf16.h>
#include <math.h>

#define MDIM 512
#define VDIM 50000
#define LSEQ 4096
#define EPW  50001     // Eprev/Enext row width
#define QPAD 528       // bf16 row stride (16B-aligned rows)
#define ITERS 6        // 5 unnormalized warm steps + 1 measured step
#define NWG  256       // 256 WGs x 16 rows = 4096 chunks
#define XTSTRIDE 4108  // ExTT row stride (floats); [4] front guard + [4096 data] + [8] tail guard
#define XTGUARD 4

typedef short short8 __attribute__((ext_vector_type(8)));
typedef float f32x4  __attribute__((ext_vector_type(4)));

__device__ __forceinline__ unsigned short f2bf(float f) {
    unsigned int x = __float_as_uint(f);
    unsigned int r = (x + 0x7fffu + ((x >> 16) & 1u)) >> 16;   // RNE
    return (unsigned short)r;
}

// async global(16B/lane) -> LDS(base + lane*16); lds base must be wave-uniform
#define GLOAD16(gsrc, ldst) \
    __builtin_amdgcn_global_load_lds((__attribute__((address_space(1))) void*)(gsrc), \
                                     (__attribute__((address_space(3))) void*)(ldst), 16, 0, 0)

// ================= K1: fused prep =================
// blocks 0..1023    : ExTT[j][t] = E[j, x[t]], j = b>>1, t-half = b&1.
//                     8-wide batched ILP gather (idx[8] -> 8 indep loads -> 8 stores):
//                     poison fills (1.2GB/iter) thrash L3, so E lines come from HBM
//                     at ~900cyc; need ~144 lines in flight per CU to cover it.
// blocks 1024..1151 : TmS bf16 MFMA-B-fragment swizzle
// blocks 1152..1167 : path score -> atomicAdd(out, -sum)
// block  1168       : beta0 + logz0 -> atomicAdd(out, logz0)
__global__ __launch_bounds__(256) void k_prep(
        const float* __restrict__ T, const float* __restrict__ E,
        const float* __restrict__ Eprev, const float* __restrict__ Enext,
        const float* __restrict__ Cap, const int* __restrict__ x,
        const int* __restrict__ y, const int* __restrict__ upper,
        unsigned short* __restrict__ TmS, float* __restrict__ beta0,
        float* __restrict__ ExTT, float* __restrict__ out) {
    __shared__ int xs[2048];               // gather: x half staged; beta0 role: reduction buf
    int b = blockIdx.x, tid = threadIdx.x;

    if (b < 1024) {
        // ---- ext gather: 2 blocks per state j, 2048 t's each, 8 loads/thread ILP ----
        int j    = b >> 1;
        int base = (b & 1) * 2048;
        for (int t = tid; t < 2048; t += 256) xs[t] = x[base + t];
        __syncthreads();
        const float* Ej  = E + (size_t)j * VDIM;
        float*       dst = ExTT + (size_t)j * XTSTRIDE + XTGUARD + base;
        int   idx[8];
        float v[8];
#pragma unroll
        for (int q = 0; q < 8; ++q) idx[q] = xs[tid + q * 256];
#pragma unroll
        for (int q = 0; q < 8; ++q) v[q] = Ej[idx[q]];
#pragma unroll
        for (int q = 0; q < 8; ++q) dst[tid + q * 256] = v[q];
    } else if (b < 1152) {
        // ---- Tm swizzle: frag g = jt<<10 | k16<<6 | lane ----
        int g = (b - 1024) * 256 + tid;    // 0..32767
        int jt = g >> 10, k16 = (g >> 6) & 15, lane = g & 63;
        int n  = jt * 16 + (lane & 15);
        int kb = k16 * 32 + (lane >> 4) * 8;
        unsigned short tmp[8];
#pragma unroll
        for (int jj = 0; jj < 8; ++jj) tmp[jj] = f2bf(T[(kb + jj) * MDIM + n]);
        uint4 v;
        v.x = tmp[0] | ((unsigned)tmp[1] << 16);
        v.y = tmp[2] | ((unsigned)tmp[3] << 16);
        v.z = tmp[4] | ((unsigned)tmp[5] << 16);
        v.w = tmp[6] | ((unsigned)tmp[7] << 16);
        *(uint4*)(TmS + (size_t)g * 8) = v;
    } else if (b < 1168) {
        // ---- path score ----
        int t = (b - 1152) * 256 + tid;    // 0..4095
        int yt = y[t];
        int yp = (t == 0) ? MDIM : y[t - 1];
        int xp = (t == 0) ? MDIM : x[t - 1];
        int xn = (t == LSEQ - 1) ? MDIM : x[t + 1];
        float v = T[yp * MDIM + yt] + Eprev[yt * EPW + xp] + Enext[yt * EPW + xn]
                + Cap[yt * 2 + upper[t]] + E[(size_t)yt * VDIM + x[t]];
#pragma unroll
        for (int m = 1; m < 64; m <<= 1) v += __shfl_xor(v, m);
        if ((tid & 63) == 0) atomicAdd(out, -v);
    } else {
        // ---- beta0 + logz0: thread handles states tid and tid+256 ----
        float* red = (float*)xs;
        int x0 = x[0], x1 = x[1], u0 = upper[0];
        float e0, e1;
#pragma unroll
        for (int h = 0; h < 2; ++h) {
            int i = tid + h * 256;
            float phi = T[MDIM * MDIM + i] + Eprev[i * EPW + MDIM] + Enext[i * EPW + x1]
                      + Cap[i * 2 + u0] + E[(size_t)i * VDIM + x0];
            float e = expf(phi);
            if (h == 0) e0 = e; else e1 = e;
        }
        red[tid] = e0 + e1;
        __syncthreads();
        for (int s = 128; s > 0; s >>= 1) {
            if (tid < s) red[tid] += red[tid + s];
            __syncthreads();
        }
        float s0 = red[0];
        beta0[tid] = e0 / s0;
        beta0[tid + 256] = e1 / s0;
        if (tid == 0) atomicAdd(out, logf(s0));
    }
}

// ================= K2: chunked forward scan =================
// Chunk c = wg*16 + r measures step t_real = c+1 at iter ITERS-1 (ratio trick).
// Iter i: step t = tw0 + r + i, tw0 = 16*wg - (ITERS-2). All steps unnormalized;
// S0 (i=ITERS-2) and S1 (i=ITERS-1) row sums -> contribution log(S1/S0).
// t==1 rows get exact beta0 injected (sum=1); S0==0 -> 1.
//
// 1024 threads = 16 waves. Tm is staged into LDS via global_load_lds, double-
// buffered per k16-phase. Wave w consumes ONLY fragments jt=w and w+16, and
// the DMA writes lds_base + lane*16 which exactly matches the fragment layout
// -> each wave stages its own 2 slots, no cross-wave sharing, no extra
// barriers; per-wave counted-vmcnt pipeline (never drained mid-loop).
// This removed the R0-R3 scratch spills (48-128 MB); R4: 103 -> ~59 us.
__global__ __launch_bounds__(1024, 4) void k_chunks(const unsigned short* __restrict__ TmS,
                                                    const float* __restrict__ beta0,
                                                    const float* __restrict__ ExTT,
                                                    float* __restrict__ out) {
    __shared__ __align__(16) unsigned short Q[16 * QPAD];
    __shared__ __align__(16) unsigned short Bst[2][32][512];   // 64 KB: [buf][jt-slot][lane*8]
    __shared__ float S0[16], S1[16];
    int tid  = threadIdx.x;
    int wg   = blockIdx.x;
    int wave = tid >> 6;        // 0..15
    int lane = tid & 63;
    int quad = lane >> 4;
    int l16  = lane & 15;
    int tw0  = 16 * wg - (ITERS - 2);

    const unsigned short* tmb0 = TmS + (size_t)((wave * 16) * 64 + lane) * 8;         // jt = wave
    const unsigned short* tmb1 = TmS + (size_t)(((wave + 16) * 16) * 64 + lane) * 8;  // jt = wave+16

    unsigned short uinit = f2bf(1.0f / 512.0f);
    for (int idx = tid; idx < 16 * MDIM; idx += 1024) {
        int r = idx >> 9, j = idx & 511;
        Q[r * QPAD + j] = uinit;
    }
    if (tid < 16) { S0[tid] = 0.f; S1[tid] = 0.f; }
    __syncthreads();

    for (int i = 0; i < ITERS; ++i) {
        // ---- A: inject exact beta0 into the row whose step is t==1 this iter
        int rinj = 1 - tw0 - i;
        if (rinj >= 0 && rinj < 16 && tid < MDIM) Q[rinj * QPAD + tid] = f2bf(beta0[tid]);
        __syncthreads();   // orders injection + prev D-writes before B-reads (drains vmcnt too)

        // ---- stage k16=0 first (starts the L2 stream earliest)
        GLOAD16(tmb0, &Bst[0][wave][0]);
        GLOAD16(tmb1, &Bst[0][wave + 16][0]);

        // ---- ev prefetch: 4 scalar floats per p (t_base..t_base+3), guarded region
        int t_base = tw0 + quad * 4 + i;   // reg r -> t = t_base + r
        float ev[2][4];
#pragma unroll
        for (int p = 0; p < 2; ++p) {
            int col = (wave + p * 16) * 16 + l16;
            const float* src = ExTT + (size_t)col * XTSTRIDE + XTGUARD + t_base;
#pragma unroll
            for (int reg = 0; reg < 4; ++reg) ev[p][reg] = src[reg];
        }

        // ---- B: G(16x512) = Q @ Tm, Tm via LDS double-buffer, counted vmcnt
        f32x4 acc0 = (f32x4){0.f, 0.f, 0.f, 0.f};
        f32x4 acc1 = (f32x4){0.f, 0.f, 0.f, 0.f};
#pragma unroll
        for (int k16 = 0; k16 < 16; ++k16) {
            if (k16 < 15) {
                int nb = (k16 + 1) & 1;
                GLOAD16(tmb0 + (size_t)(k16 + 1) * 512, &Bst[nb][wave][0]);
                GLOAD16(tmb1 + (size_t)(k16 + 1) * 512, &Bst[nb][wave + 16][0]);
            }
            // in-flight order: [stage k16 (2)] [ev (8, k16==0 only)] [stage k16+1 (2)]
            // wait so that stage k16 is complete; keep the newest loads in flight.
            if (k16 == 0)       asm volatile("s_waitcnt vmcnt(10)" ::: "memory");
            else if (k16 < 15)  asm volatile("s_waitcnt vmcnt(2)"  ::: "memory");
            else                asm volatile("s_waitcnt vmcnt(0)"  ::: "memory");
            short8 a  = *(const short8*)&Q[l16 * QPAD + k16 * 32 + quad * 8];
            short8 b0 = *(const short8*)&Bst[k16 & 1][wave][lane * 8];
            short8 b1 = *(const short8*)&Bst[k16 & 1][wave + 16][lane * 8];
            acc0 = __builtin_amdgcn_mfma_f32_16x16x32_bf16(a, b0, acc0, 0, 0, 0);
            acc1 = __builtin_amdgcn_mfma_f32_16x16x32_bf16(a, b1, acc1, 0, 0, 0);
        }
        __syncthreads();   // all Q reads done before rewrite

        // ---- C: alpha = G .* ext; reduce row sums on last two iters only
        bool red = (i >= ITERS - 2);
        float* Sx = (i == ITERS - 2) ? S0 : S1;
        float av0[4], av1[4];
        float srow[4];
#pragma unroll
        for (int reg = 0; reg < 4; ++reg) {
            int t = t_base + reg;
            bool ok = (t >= 1 && t < LSEQ);
            float v0 = ok ? acc0[reg] * ev[0][reg] : 0.f;
            float v1 = ok ? acc1[reg] * ev[1][reg] : 0.f;
            av0[reg] = v0;
            av1[reg] = v1;
            if (red) {
                float sv = v0 + v1;        // both p land in the same row quad*4+reg
                sv += __shfl_xor(sv, 1);
                sv += __shfl_xor(sv, 2);
                sv += __shfl_xor(sv, 4);
                sv += __shfl_xor(sv, 8);
                srow[reg] = sv;
            }
        }
        if (red && l16 == 0) {
#pragma unroll
            for (int reg = 0; reg < 4; ++reg)
                atomicAdd(&Sx[quad * 4 + reg], srow[reg]);
        }

        // ---- D: write back bf16 (skip after final step)
        if (i < ITERS - 1) {
#pragma unroll
            for (int p = 0; p < 2; ++p) {
                int col = (wave + p * 16) * 16 + l16;
#pragma unroll
                for (int reg = 0; reg < 4; ++reg) {
                    int row = quad * 4 + reg;
                    int t = t_base + reg;
                    if (t >= 1 && t < LSEQ)
                        Q[row * QPAD + col] = f2bf(p ? av1[reg] : av0[reg]);
                }
            }
        }
        // no trailing barrier: next iter's post-A barrier orders D before B-reads;
        // the next injection row had t==0 here -> its D write was guarded out.
    }
    __syncthreads();   // S0/S1 atomicAdds complete before read

    if (wave == 0) {
        float lv = 0.f;
        int tr = 16 * wg + lane + 1;
        if (lane < 16 && tr < LSEQ) {
            float s0 = S0[lane];
            if (s0 == 0.f) s0 = 1.f;   // t_real==1 row: injected beta0 has sum 1
            lv = logf(S1[lane] / s0);
        }
#pragma unroll
        for (int m = 1; m < 64; m <<= 1) lv += __shfl_xor(lv, m);
        if (lane == 0) atomicAdd(out, lv);
    }
}

extern "C" void kernel_launch(void* const* d_in, const int* in_sizes, int n_in,
                              void* d_out, int out_size, void* d_ws, size_t ws_size,
                              hipStream_t stream) {
    const float* T     = (const float*)d_in[0];
    const float* E     = (const float*)d_in[1];
    const float* Eprev = (const float*)d_in[2];
    const float* Enext = (const float*)d_in[3];
    const float* Cap   = (const float*)d_in[4];
    const int*   x     = (const int*)d_in[5];
    const int*   y     = (const int*)d_in[6];
    const int*   upper = (const int*)d_in[7];
    float* out = (float*)d_out;

    // ws: [0,512K) TmS | [512K,+2K) beta0 | ExTT 512*4108*4 B ~= 8.41 MB. Total ~8.94 MB.
    char* ws = (char*)d_ws;
    unsigned short* TmS = (unsigned short*)ws;
    float* beta0 = (float*)(ws + 524288);
    float* ExTT  = (float*)(ws + 524288 + 2048);

    hipMemsetAsync(out, 0, sizeof(float), stream);
    k_prep<<<1169, 256, 0, stream>>>(T, E, Eprev, Enext, Cap, x, y, upper,
                                     TmS, beta0, ExTT, out);
    k_chunks<<<NWG, 1024, 0, stream>>>(TmS, beta0, ExTT, out);
}